// Round 1
// baseline (4918.267 us; speedup 1.0000x reference)
//
#include <hip/hip_runtime.h>
#include <stdint.h>

#define GG 64
#define NN 256
#define FF 20
#define HH 32
#define KK 5
#define NS 100

// out offsets (floats)
#define O_PT   0
#define O_LA   20971520
#define O_ZMU  20971840
#define O_LOSS 21496128

// ws offsets (floats)
#define W_HA   0
#define W_LT   524288          /* [K][G][N][N] */
#define W_PART 21495808        /* [NS*G] */

__device__ __forceinline__ uint32_t rotl32(uint32_t v, int n){ return (v << n) | (v >> (32 - n)); }

// JAX threefry2x32 (20 rounds), key (k0,k1), counter (x0,x1)
__device__ __forceinline__ void tf2x32(uint32_t k0, uint32_t k1, uint32_t x0, uint32_t x1,
                                       uint32_t& o0, uint32_t& o1){
  uint32_t k2 = k0 ^ k1 ^ 0x1BD11BDAu;
  x0 += k0; x1 += k1;
  x0 += x1; x1 = rotl32(x1,13); x1 ^= x0;
  x0 += x1; x1 = rotl32(x1,15); x1 ^= x0;
  x0 += x1; x1 = rotl32(x1,26); x1 ^= x0;
  x0 += x1; x1 = rotl32(x1, 6); x1 ^= x0;
  x0 += k1; x1 += k2 + 1u;
  x0 += x1; x1 = rotl32(x1,17); x1 ^= x0;
  x0 += x1; x1 = rotl32(x1,29); x1 ^= x0;
  x0 += x1; x1 = rotl32(x1,16); x1 ^= x0;
  x0 += x1; x1 = rotl32(x1,24); x1 ^= x0;
  x0 += k2; x1 += k0 + 2u;
  x0 += x1; x1 = rotl32(x1,13); x1 ^= x0;
  x0 += x1; x1 = rotl32(x1,15); x1 ^= x0;
  x0 += x1; x1 = rotl32(x1,26); x1 ^= x0;
  x0 += x1; x1 = rotl32(x1, 6); x1 ^= x0;
  x0 += k0; x1 += k1 + 3u;
  x0 += x1; x1 = rotl32(x1,17); x1 ^= x0;
  x0 += x1; x1 = rotl32(x1,29); x1 ^= x0;
  x0 += x1; x1 = rotl32(x1,16); x1 ^= x0;
  x0 += x1; x1 = rotl32(x1,24); x1 ^= x0;
  x0 += k1; x1 += k2 + 4u;
  x0 += x1; x1 = rotl32(x1,13); x1 ^= x0;
  x0 += x1; x1 = rotl32(x1,15); x1 ^= x0;
  x0 += x1; x1 = rotl32(x1,26); x1 ^= x0;
  x0 += x1; x1 = rotl32(x1, 6); x1 ^= x0;
  o0 = x0 + k2; o1 = x1 + k0 + 5u;
}

__device__ __forceinline__ float u01(uint32_t b){
  return __uint_as_float((b >> 9) | 0x3f800000u) - 1.0f;
}

// XLA ErfInv32 (Giles 2012)
__device__ __forceinline__ float erfinv_f(float x){
  float w = -log1pf(-x*x);
  float p;
  if (w < 5.f){
    w = w - 2.5f;
    p = 2.81022636e-08f;
    p = fmaf(p,w, 3.43273939e-07f);
    p = fmaf(p,w,-3.5233877e-06f);
    p = fmaf(p,w,-4.39150654e-06f);
    p = fmaf(p,w, 0.00021858087f);
    p = fmaf(p,w,-0.00125372503f);
    p = fmaf(p,w,-0.00417768164f);
    p = fmaf(p,w, 0.246640727f);
    p = fmaf(p,w, 1.50140941f);
  } else {
    w = sqrtf(w) - 3.f;
    p = -0.000200214257f;
    p = fmaf(p,w, 0.000100950558f);
    p = fmaf(p,w, 0.00134934322f);
    p = fmaf(p,w,-0.00367342844f);
    p = fmaf(p,w, 0.00573950773f);
    p = fmaf(p,w,-0.0076224613f);
    p = fmaf(p,w, 0.00943887047f);
    p = fmaf(p,w, 1.00167406f);
    p = fmaf(p,w, 2.83297682f);
  }
  return p*x;
}

// ---------- K1: per-node encoders: Z_mu -> out, ha -> ws ----------
__global__ void k_encode(const float* __restrict__ X,
                         const float* __restrict__ Wz1, const float* __restrict__ bz1,
                         const float* __restrict__ Wz2, const float* __restrict__ bz2,
                         const float* __restrict__ Wa1, const float* __restrict__ ba1,
                         float* __restrict__ out, float* __restrict__ ws){
  int g = blockIdx.y, nt = blockIdx.x;   // nt 0..31 (8 nodes each)
  int tid = threadIdx.x;
  int nl = tid >> 5, h = tid & 31;
  __shared__ float xrow[8][FF];
  __shared__ float hzrow[8][HH];
  if (tid < 8*FF){
    int a = tid / FF, b = tid % FF;
    xrow[a][b] = X[(g*NN + nt*8 + a)*FF + b];
  }
  __syncthreads();
  float hz = bz1[h], ha = ba1[h];
  for (int f = 0; f < FF; ++f){
    float xv = xrow[nl][f];
    hz = fmaf(xv, Wz1[f*HH + h], hz);
    ha = fmaf(xv, Wa1[f*HH + h], ha);
  }
  hz = fmaxf(hz, 0.f); ha = fmaxf(ha, 0.f);
  hzrow[nl][h] = hz;
  int n = nt*8 + nl;
  ws[W_HA + (g*NN + n)*HH + h] = ha;
  __syncthreads();
  float zm = bz2[h];
  for (int hh = 0; hh < HH; ++hh)
    zm = fmaf(hzrow[nl][hh], Wz2[hh*HH + h], zm);
  out[O_ZMU + (g*NN + n)*HH + h] = zm;
}

// ---------- K2: logit_alpha = mean_n(ha) @ Walpha + balpha ----------
__global__ void k_alpha(const float* __restrict__ Walpha, const float* __restrict__ balpha,
                        float* __restrict__ out, const float* __restrict__ ws){
  int g = blockIdx.x; int tid = threadIdx.x;
  int h = tid & 31, p = tid >> 5;  // p 0..7
  __shared__ float sums[8][HH];
  __shared__ float meanh[HH];
  float s = 0.f;
  for (int n = p; n < NN; n += 8) s += ws[W_HA + (g*NN + n)*HH + h];
  sums[p][h] = s;
  __syncthreads();
  if (p == 0){
    float t = 0.f;
    for (int q = 0; q < 8; ++q) t += sums[q][h];
    meanh[h] = t * (1.0f/256.0f);
  }
  __syncthreads();
  if (tid < KK){
    float la = balpha[tid];
    for (int hh = 0; hh < HH; ++hh) la = fmaf(meanh[hh], Walpha[hh*KK + tid], la);
    out[O_LA + g*KK + tid] = la;
  }
}

// ---------- K3: logit_theta (ws, k-major) + prob_theta (out) ----------
__global__ void k_theta(const float* __restrict__ Wtheta,
                        float* __restrict__ out, float* __restrict__ ws){
  int jt = blockIdx.x, it = blockIdx.y, g = blockIdx.z;
  int tid = threadIdx.x;
  __shared__ float wth[HH*HH*KK];     // [h][f*K+k]
  __shared__ float hai[16][HH], haj[16][HH];
  __shared__ float tloc[16][HH*KK];   // [i][f*K+k]
  for (int idx = tid; idx < HH*HH*KK; idx += 256) wth[idx] = Wtheta[idx];
  for (int idx = tid; idx < 16*HH; idx += 256){
    int r = idx >> 5, c = idx & 31;
    hai[r][c] = ws[W_HA + (g*NN + it*16 + r)*HH + c];
    haj[r][c] = ws[W_HA + (g*NN + jt*16 + r)*HH + c];
  }
  __syncthreads();
  for (int idx = tid; idx < 16*HH*KK; idx += 256){
    int i = idx / (HH*KK), rem = idx % (HH*KK);
    float a = 0.f;
    for (int hh = 0; hh < HH; ++hh) a = fmaf(hai[i][hh], wth[hh*(HH*KK) + rem], a);
    tloc[i][rem] = a;
  }
  __syncthreads();
  int il = tid >> 4, jl = tid & 15;
  float acc[KK] = {0,0,0,0,0};
  for (int f = 0; f < HH; ++f){
    float hv = haj[jl][f];
    #pragma unroll
    for (int k = 0; k < KK; ++k) acc[k] = fmaf(tloc[il][f*KK+k], hv, acc[k]);
  }
  int i = it*16 + il, j = jt*16 + jl;
  #pragma unroll
  for (int k = 0; k < KK; ++k){
    float v = acc[k];
    ws[W_LT + ((size_t)k*GG + g)*NN*NN + i*NN + j] = v;
    float pr = (i == j) ? 0.f : (1.f / (1.f + expf(-v)));
    out[O_PT + ((size_t)(g*NN + i)*NN + j)*KK + k] = pr;
  }
}

// ---------- K4: the whole MC loop, one block per (it, g) ----------
__global__ __launch_bounds__(512)
void k_loop(const float* __restrict__ Wd1, const float* __restrict__ bd1,
            const float* __restrict__ Wd2, const float* __restrict__ bd2,
            const float* __restrict__ X, const int* __restrict__ seedp,
            const float* __restrict__ outro, float* __restrict__ ws){
  int g  = blockIdx.x;   // 0..63
  int it = blockIdx.y;   // 0..99
  int tid = threadIdx.x; // 0..511

  __shared__ float bufA[NN*HH];      // Zs, then h     (32KB)
  __shared__ float bufB[NN*HH];      // az, then ah    (32KB)
  __shared__ uint32_t Abits[NN*8];   // adjacency bits (8KB) — reused as reduce buf
  __shared__ float wd1[HH*HH], bd1s[HH];
  __shared__ float wd2[HH*FF], bd2s[FF];
  __shared__ uint32_t skey[6];
  __shared__ int skmax;

  if (tid == 0){
    uint32_t seed = (uint32_t)(*seedp);
    uint32_t b0, b1, a0, a1, c0, c1, d0, d1;
    tf2x32(0u, seed, 0u, (uint32_t)it, b0, b1);  // fold_in(base, it)
    tf2x32(b0, b1, 0u, 0u, a0, a1);              // split -> k1
    tf2x32(b0, b1, 0u, 1u, c0, c1);              // k2
    tf2x32(b0, b1, 0u, 2u, d0, d1);              // k3
    skey[0]=a0; skey[1]=a1; skey[2]=c0; skey[3]=c1; skey[4]=d0; skey[5]=d1;
  }
  for (int idx = tid; idx < HH*HH; idx += 512) wd1[idx] = Wd1[idx];
  for (int idx = tid; idx < HH*FF; idx += 512) wd2[idx] = Wd2[idx];
  if (tid < HH) bd1s[tid] = bd1[tid];
  if (tid < FF) bd2s[tid] = bd2[tid];
  for (int idx = tid; idx < NN*8; idx += 512) Abits[idx] = 0u;
  __syncthreads();

  // gumbel-softmax hard component selection (argmax == argmax of logits+g)
  if (tid == 0){
    float best = -3.4e38f; int arg = 0;
    for (int k = 0; k < KK; ++k){
      uint32_t e = (uint32_t)(g*KK + k), r0, r1;
      tf2x32(skey[2], skey[3], 0u, e, r0, r1);
      float f = u01(r0 ^ r1);
      float u = fmaxf(1.17549435e-38f, f + 1.17549435e-38f);
      float gum = -logf(-logf(u));
      float z = outro[O_LA + g*KK + k] + gum;
      if (z > best){ best = z; arg = k; }
    }
    skmax = arg;
  }
  // sample_Z = Z_mu + std * normal
  for (int idx = tid; idx < NN*HH; idx += 512){
    uint32_t e = (uint32_t)(g*NN*HH + idx), r0, r1;
    tf2x32(skey[0], skey[1], 0u, e, r0, r1);
    float f = u01(r0 ^ r1);
    float u = fmaf(f, 2.0f, -0.99999994f);       // hi-lo rounds to exactly 2.0f
    float nrm = 1.41421356f * erfinv_f(u);
    bufA[idx] = outro[O_ZMU + g*NN*HH + idx] + 0.22313016f * nrm;
  }
  __syncthreads();

  // binary concrete -> hard adjacency bits (strict lower triangle, symmetrized)
  {
    const float UMIN = 1e-6f;
    const float UR   = (1.0f - 1e-6f) - 1e-6f;
    int kmax = skmax;
    const float* ltg = ws + W_LT + ((size_t)kmax*GG + g)*NN*NN;
    for (int idx = tid; idx < NN*NN; idx += 512){
      int i = idx >> 8, j = idx & 255;
      if (i <= j) continue;
      uint32_t e = (uint32_t)(g*NN*NN + idx), r0, r1;
      tf2x32(skey[4], skey[5], 0u, e, r0, r1);
      float f = u01(r0 ^ r1);
      float u = fmaxf(UMIN, fmaf(f, UR, UMIN));
      float logistic = logf(u) - log1pf(-u);
      float x = (ltg[i*NN + j] + logistic) * 2.0f;   // / TAU
      if (x > 0.f){
        atomicOr(&Abits[i*8 + (j >> 5)], 1u << (j & 31));
        atomicOr(&Abits[j*8 + (i >> 5)], 1u << (i & 31));
      }
    }
  }
  __syncthreads();

  int r = tid >> 5, h = tid & 31;   // r 0..15 ; rows handled: i = rt*16 + r
  float acc[16];

  // AZ = A @ Zs  (bit-masked accumulation, z reused across 16 rows)
  #pragma unroll
  for (int rt = 0; rt < 16; ++rt) acc[rt] = 0.f;
  for (int jw = 0; jw < 8; ++jw){
    uint32_t wv[16];
    #pragma unroll
    for (int rt = 0; rt < 16; ++rt) wv[rt] = Abits[(rt*16 + r)*8 + jw];
    #pragma unroll
    for (int b = 0; b < 32; ++b){
      float z = bufA[(jw*32 + b)*HH + h];
      #pragma unroll
      for (int rt = 0; rt < 16; ++rt){
        float m = (float)((wv[rt] >> b) & 1u);
        acc[rt] = fmaf(m, z, acc[rt]);
      }
    }
  }
  #pragma unroll
  for (int rt = 0; rt < 16; ++rt) bufB[(rt*16 + r)*HH + h] = acc[rt];
  __syncthreads();

  // h = relu(AZ @ Wd1 + bd1) -> bufA (Zs dead)
  #pragma unroll
  for (int rt = 0; rt < 16; ++rt){
    int i = rt*16 + r;
    float hv = bd1s[h];
    #pragma unroll
    for (int hh = 0; hh < HH; ++hh)
      hv = fmaf(bufB[i*HH + hh], wd1[hh*HH + h], hv);
    acc[rt] = fmaxf(hv, 0.f);
  }
  __syncthreads();
  #pragma unroll
  for (int rt = 0; rt < 16; ++rt) bufA[(rt*16 + r)*HH + h] = acc[rt];
  __syncthreads();

  // Ah = A @ h -> bufB (az dead)
  #pragma unroll
  for (int rt = 0; rt < 16; ++rt) acc[rt] = 0.f;
  for (int jw = 0; jw < 8; ++jw){
    uint32_t wv[16];
    #pragma unroll
    for (int rt = 0; rt < 16; ++rt) wv[rt] = Abits[(rt*16 + r)*8 + jw];
    #pragma unroll
    for (int b = 0; b < 32; ++b){
      float z = bufA[(jw*32 + b)*HH + h];
      #pragma unroll
      for (int rt = 0; rt < 16; ++rt){
        float m = (float)((wv[rt] >> b) & 1u);
        acc[rt] = fmaf(m, z, acc[rt]);
      }
    }
  }
  #pragma unroll
  for (int rt = 0; rt < 16; ++rt) bufB[(rt*16 + r)*HH + h] = acc[rt];
  __syncthreads();

  // Xmu = Ah @ Wd2 + bd2 ; accumulate squared error
  float part = 0.f;
  if (h < FF){
    #pragma unroll
    for (int rt = 0; rt < 16; ++rt){
      int i = rt*16 + r;
      float xm = bd2s[h];
      #pragma unroll
      for (int hh = 0; hh < HH; ++hh)
        xm = fmaf(bufB[i*HH + hh], wd2[hh*FF + h], xm);
      float d = xm - X[((size_t)g*NN + i)*FF + h];
      part = fmaf(d, d, part);
    }
  }
  // block reduce (reuse Abits as float scratch; all Abits reads are done)
  float* red = (float*)Abits;
  red[tid] = part;
  __syncthreads();
  for (int s = 256; s > 0; s >>= 1){
    if (tid < s) red[tid] += red[tid + s];
    __syncthreads();
  }
  if (tid == 0) ws[W_PART + it*GG + g] = red[0];
}

// ---------- K5: final loss reduction ----------
__global__ void k_final(float* __restrict__ out, const float* __restrict__ ws){
  int tid = threadIdx.x;
  double s = 0.0;
  for (int i = tid; i < NS*GG; i += 512) s += (double)ws[W_PART + i];
  __shared__ double rd[512];
  rd[tid] = s;
  __syncthreads();
  for (int st = 256; st > 0; st >>= 1){
    if (tid < st) rd[tid] += rd[tid + st];
    __syncthreads();
  }
  if (tid == 0) out[O_LOSS] = (float)(rd[0] * (0.5/6400.0));
}

extern "C" void kernel_launch(void* const* d_in, const int* in_sizes, int n_in,
                              void* d_out, int out_size, void* d_ws, size_t ws_size,
                              hipStream_t stream){
  const float* X   = (const float*)d_in[0];
  const float* Wz1 = (const float*)d_in[1];
  const float* bz1 = (const float*)d_in[2];
  const float* Wz2 = (const float*)d_in[3];
  const float* bz2 = (const float*)d_in[4];
  const float* Wa1 = (const float*)d_in[5];
  const float* ba1 = (const float*)d_in[6];
  const float* Wth = (const float*)d_in[7];
  const float* Wal = (const float*)d_in[8];
  const float* bal = (const float*)d_in[9];
  const float* Wd1 = (const float*)d_in[10];
  const float* bd1 = (const float*)d_in[11];
  const float* Wd2 = (const float*)d_in[12];
  const float* bd2 = (const float*)d_in[13];
  const int* seed  = (const int*)d_in[14];
  float* out = (float*)d_out;
  float* ws  = (float*)d_ws;

  hipLaunchKernelGGL(k_encode, dim3(32,64), dim3(256), 0, stream,
                     X, Wz1, bz1, Wz2, bz2, Wa1, ba1, out, ws);
  hipLaunchKernelGGL(k_alpha, dim3(64), dim3(256), 0, stream, Wal, bal, out, ws);
  hipLaunchKernelGGL(k_theta, dim3(16,16,64), dim3(256), 0, stream, Wth, out, ws);
  hipLaunchKernelGGL(k_loop, dim3(64,100), dim3(512), 0, stream,
                     Wd1, bd1, Wd2, bd2, X, seed, out, ws);
  hipLaunchKernelGGL(k_final, dim3(1), dim3(512), 0, stream, out, ws);
}

// Round 2
// 1870.212 us; speedup vs baseline: 2.6298x; 2.6298x over previous
//
#include <hip/hip_runtime.h>
#include <stdint.h>

#define GG 64
#define NN 256
#define FF 20
#define HH 32
#define KK 5
#define NS 100

// out offsets (floats)
#define O_PT   0
#define O_LA   20971520
#define O_ZMU  20971840
#define O_LOSS 21496128

// ws offsets (floats)
#define W_HA   0
#define W_LT   524288          /* [K][G][N][N] threshold = sigmoid(-logit) */
#define W_PART 21495808        /* [NS*G] */

typedef __attribute__((ext_vector_type(8))) short short8v;
typedef __attribute__((ext_vector_type(4))) float float4v;

__device__ __forceinline__ uint32_t rotl32(uint32_t v, int n){ return (v << n) | (v >> (32 - n)); }

// JAX threefry2x32 (20 rounds), key (k0,k1), counter (x0,x1)
__device__ __forceinline__ void tf2x32(uint32_t k0, uint32_t k1, uint32_t x0, uint32_t x1,
                                       uint32_t& o0, uint32_t& o1){
  uint32_t k2 = k0 ^ k1 ^ 0x1BD11BDAu;
  x0 += k0; x1 += k1;
  x0 += x1; x1 = rotl32(x1,13); x1 ^= x0;
  x0 += x1; x1 = rotl32(x1,15); x1 ^= x0;
  x0 += x1; x1 = rotl32(x1,26); x1 ^= x0;
  x0 += x1; x1 = rotl32(x1, 6); x1 ^= x0;
  x0 += k1; x1 += k2 + 1u;
  x0 += x1; x1 = rotl32(x1,17); x1 ^= x0;
  x0 += x1; x1 = rotl32(x1,29); x1 ^= x0;
  x0 += x1; x1 = rotl32(x1,16); x1 ^= x0;
  x0 += x1; x1 = rotl32(x1,24); x1 ^= x0;
  x0 += k2; x1 += k0 + 2u;
  x0 += x1; x1 = rotl32(x1,13); x1 ^= x0;
  x0 += x1; x1 = rotl32(x1,15); x1 ^= x0;
  x0 += x1; x1 = rotl32(x1,26); x1 ^= x0;
  x0 += x1; x1 = rotl32(x1, 6); x1 ^= x0;
  x0 += k0; x1 += k1 + 3u;
  x0 += x1; x1 = rotl32(x1,17); x1 ^= x0;
  x0 += x1; x1 = rotl32(x1,29); x1 ^= x0;
  x0 += x1; x1 = rotl32(x1,16); x1 ^= x0;
  x0 += x1; x1 = rotl32(x1,24); x1 ^= x0;
  x0 += k1; x1 += k2 + 4u;
  x0 += x1; x1 = rotl32(x1,13); x1 ^= x0;
  x0 += x1; x1 = rotl32(x1,15); x1 ^= x0;
  x0 += x1; x1 = rotl32(x1,26); x1 ^= x0;
  x0 += x1; x1 = rotl32(x1, 6); x1 ^= x0;
  o0 = x0 + k2; o1 = x1 + k0 + 5u;
}

__device__ __forceinline__ float u01(uint32_t b){
  return __uint_as_float((b >> 9) | 0x3f800000u) - 1.0f;
}

__device__ __forceinline__ unsigned short f2bf(float f){
  uint32_t u = __float_as_uint(f);
  uint32_t r = u + 0x7FFFu + ((u >> 16) & 1u);
  return (unsigned short)(r >> 16);
}

// XLA ErfInv32 (Giles 2012)
__device__ __forceinline__ float erfinv_f(float x){
  float w = -log1pf(-x*x);
  float p;
  if (w < 5.f){
    w = w - 2.5f;
    p = 2.81022636e-08f;
    p = fmaf(p,w, 3.43273939e-07f);
    p = fmaf(p,w,-3.5233877e-06f);
    p = fmaf(p,w,-4.39150654e-06f);
    p = fmaf(p,w, 0.00021858087f);
    p = fmaf(p,w,-0.00125372503f);
    p = fmaf(p,w,-0.00417768164f);
    p = fmaf(p,w, 0.246640727f);
    p = fmaf(p,w, 1.50140941f);
  } else {
    w = sqrtf(w) - 3.f;
    p = -0.000200214257f;
    p = fmaf(p,w, 0.000100950558f);
    p = fmaf(p,w, 0.00134934322f);
    p = fmaf(p,w,-0.00367342844f);
    p = fmaf(p,w, 0.00573950773f);
    p = fmaf(p,w,-0.0076224613f);
    p = fmaf(p,w, 0.00943887047f);
    p = fmaf(p,w, 1.00167406f);
    p = fmaf(p,w, 2.83297682f);
  }
  return p*x;
}

// ---------- K1: per-node encoders: Z_mu -> out, ha -> ws ----------
__global__ void k_encode(const float* __restrict__ X,
                         const float* __restrict__ Wz1, const float* __restrict__ bz1,
                         const float* __restrict__ Wz2, const float* __restrict__ bz2,
                         const float* __restrict__ Wa1, const float* __restrict__ ba1,
                         float* __restrict__ out, float* __restrict__ ws){
  int g = blockIdx.y, nt = blockIdx.x;   // nt 0..31 (8 nodes each)
  int tid = threadIdx.x;
  int nl = tid >> 5, h = tid & 31;
  __shared__ float xrow[8][FF];
  __shared__ float hzrow[8][HH];
  if (tid < 8*FF){
    int a = tid / FF, b = tid % FF;
    xrow[a][b] = X[(g*NN + nt*8 + a)*FF + b];
  }
  __syncthreads();
  float hz = bz1[h], ha = ba1[h];
  for (int f = 0; f < FF; ++f){
    float xv = xrow[nl][f];
    hz = fmaf(xv, Wz1[f*HH + h], hz);
    ha = fmaf(xv, Wa1[f*HH + h], ha);
  }
  hz = fmaxf(hz, 0.f); ha = fmaxf(ha, 0.f);
  hzrow[nl][h] = hz;
  int n = nt*8 + nl;
  ws[W_HA + (g*NN + n)*HH + h] = ha;
  __syncthreads();
  float zm = bz2[h];
  for (int hh = 0; hh < HH; ++hh)
    zm = fmaf(hzrow[nl][hh], Wz2[hh*HH + h], zm);
  out[O_ZMU + (g*NN + n)*HH + h] = zm;
}

// ---------- K2: logit_alpha = mean_n(ha) @ Walpha + balpha ----------
__global__ void k_alpha(const float* __restrict__ Walpha, const float* __restrict__ balpha,
                        float* __restrict__ out, const float* __restrict__ ws){
  int g = blockIdx.x; int tid = threadIdx.x;
  int h = tid & 31, p = tid >> 5;  // p 0..7
  __shared__ float sums[8][HH];
  __shared__ float meanh[HH];
  float s = 0.f;
  for (int n = p; n < NN; n += 8) s += ws[W_HA + (g*NN + n)*HH + h];
  sums[p][h] = s;
  __syncthreads();
  if (p == 0){
    float t = 0.f;
    for (int q = 0; q < 8; ++q) t += sums[q][h];
    meanh[h] = t * (1.0f/256.0f);
  }
  __syncthreads();
  if (tid < KK){
    float la = balpha[tid];
    for (int hh = 0; hh < HH; ++hh) la = fmaf(meanh[hh], Walpha[hh*KK + tid], la);
    out[O_LA + g*KK + tid] = la;
  }
}

// ---------- K3: prob_theta (out) + threshold sigmoid(-logit) (ws, k-major) ----------
__global__ void k_theta(const float* __restrict__ Wtheta,
                        float* __restrict__ out, float* __restrict__ ws){
  int jt = blockIdx.x, it = blockIdx.y, g = blockIdx.z;
  int tid = threadIdx.x;
  __shared__ float wth[HH*HH*KK];     // [h][f*K+k]
  __shared__ float hai[16][HH], haj[16][HH];
  __shared__ float tloc[16][HH*KK];   // [i][f*K+k]
  for (int idx = tid; idx < HH*HH*KK; idx += 256) wth[idx] = Wtheta[idx];
  for (int idx = tid; idx < 16*HH; idx += 256){
    int r = idx >> 5, c = idx & 31;
    hai[r][c] = ws[W_HA + (g*NN + it*16 + r)*HH + c];
    haj[r][c] = ws[W_HA + (g*NN + jt*16 + r)*HH + c];
  }
  __syncthreads();
  for (int idx = tid; idx < 16*HH*KK; idx += 256){
    int i = idx / (HH*KK), rem = idx % (HH*KK);
    float a = 0.f;
    for (int hh = 0; hh < HH; ++hh) a = fmaf(hai[i][hh], wth[hh*(HH*KK) + rem], a);
    tloc[i][rem] = a;
  }
  __syncthreads();
  int il = tid >> 4, jl = tid & 15;
  float acc[KK] = {0,0,0,0,0};
  for (int f = 0; f < HH; ++f){
    float hv = haj[jl][f];
    #pragma unroll
    for (int k = 0; k < KK; ++k) acc[k] = fmaf(tloc[il][f*KK+k], hv, acc[k]);
  }
  int i = it*16 + il, j = jt*16 + jl;
  #pragma unroll
  for (int k = 0; k < KK; ++k){
    float v = acc[k];
    float s = 1.f / (1.f + expf(-v));
    ws[W_LT + ((size_t)k*GG + g)*NN*NN + i*NN + j] = 1.f - s;   // sigmoid(-v)
    out[O_PT + ((size_t)(g*NN + i)*NN + j)*KK + k] = (i == j) ? 0.f : s;
  }
}

// ---------- K4: the whole MC loop, one block per (it, g) ----------
__global__ __launch_bounds__(512, 4)
void k_loop(const float* __restrict__ Wd1, const float* __restrict__ bd1,
            const float* __restrict__ Wd2, const float* __restrict__ bd2,
            const float* __restrict__ X, const int* __restrict__ seedp,
            const float* __restrict__ outro, float* __restrict__ ws){
  int g  = blockIdx.x;   // 0..63
  int it = blockIdx.y;   // 0..99
  int tid = threadIdx.x; // 0..511
  int lane = tid & 63, wvid = tid >> 6;
  int l15 = lane & 15, l4 = lane >> 4;

  __shared__ unsigned short zT[HH][264];  // bf16 Z^T, reused as h^T   (16.9KB)
  __shared__ uint32_t Abits[NN*8];        // adjacency bits (8KB), reused as reduce buf
  __shared__ float azf[NN][HH];           // AZ (f32), reused as Ah    (32KB)
  __shared__ float wd1s[HH*HH], bd1s[HH];
  __shared__ float wd2s[HH*FF], bd2s[FF];
  __shared__ uint32_t skey[6];
  __shared__ int skmax;

  if (tid == 0){
    uint32_t seed = (uint32_t)(*seedp);
    uint32_t b0, b1, a0, a1, c0, c1, d0, d1;
    tf2x32(0u, seed, 0u, (uint32_t)it, b0, b1);  // fold_in(base, it)
    tf2x32(b0, b1, 0u, 0u, a0, a1);              // split -> k1
    tf2x32(b0, b1, 0u, 1u, c0, c1);              // k2
    tf2x32(b0, b1, 0u, 2u, d0, d1);              // k3
    skey[0]=a0; skey[1]=a1; skey[2]=c0; skey[3]=c1; skey[4]=d0; skey[5]=d1;
    // gumbel-softmax hard component selection
    float best = -3.4e38f; int arg = 0;
    for (int k = 0; k < KK; ++k){
      uint32_t e = (uint32_t)(g*KK + k), r0, r1;
      tf2x32(c0, c1, 0u, e, r0, r1);
      float f = u01(r0 ^ r1);
      float u = fmaxf(1.17549435e-38f, f + 1.17549435e-38f);
      float gum = -logf(-logf(u));
      float z = outro[O_LA + g*KK + k] + gum;
      if (z > best){ best = z; arg = k; }
    }
    skmax = arg;
  }
  for (int idx = tid; idx < HH*HH; idx += 512) wd1s[idx] = Wd1[idx];
  for (int idx = tid; idx < HH*FF; idx += 512) wd2s[idx] = Wd2[idx];
  if (tid < HH) bd1s[tid] = bd1[tid];
  if (tid < FF) bd2s[tid] = bd2[tid];
  for (int idx = tid; idx < NN*8; idx += 512) Abits[idx] = 0u;
  __syncthreads();

  // ---- phase 1: sample_Z = Z_mu + std*normal -> zT (bf16, transposed) ----
  for (int idx = tid; idx < NN*HH; idx += 512){
    int n = idx >> 5, h = idx & 31;
    uint32_t e = (uint32_t)(g*NN*HH + idx), r0, r1;
    tf2x32(skey[0], skey[1], 0u, e, r0, r1);
    float f = u01(r0 ^ r1);
    float u = fmaf(f, 2.0f, -0.99999994f);
    float nrm = 1.41421356f * erfinv_f(u);
    float zf = outro[O_ZMU + g*NN*HH + idx] + 0.22313016f * nrm;
    zT[h][n] = f2bf(zf);
  }
  __syncthreads();

  // ---- phase 2: binary concrete -> adjacency bits (u > sigmoid(-logit)) ----
  {
    const float UMIN = 1e-6f;
    const float UR   = (1.0f - 1e-6f) - 1e-6f;
    const float* thr = ws + W_LT + ((size_t)skmax*GG + g)*NN*NN;
    for (int idx = tid; idx < NN*NN; idx += 512){
      int i = idx >> 8, j = idx & 255;
      if (i <= j) continue;
      uint32_t e = (uint32_t)(g*NN*NN + idx), r0, r1;
      tf2x32(skey[4], skey[5], 0u, e, r0, r1);
      float f = u01(r0 ^ r1);
      float u = fmaxf(UMIN, fmaf(f, UR, UMIN));
      if (u > thr[i*NN + j]){
        atomicOr(&Abits[i*8 + (j >> 5)], 1u << (j & 31));
        atomicOr(&Abits[j*8 + (i >> 5)], 1u << (i & 31));
      }
    }
  }
  __syncthreads();

  // ---- phase 3: AZ = A @ Zs via MFMA (bf16 in, f32 out) ----
  #pragma unroll
  for (int rr = 0; rr < 2; ++rr){
    int rt = wvid*2 + rr;
    int row = rt*16 + l15;
    float4v acc0 = {0.f,0.f,0.f,0.f}, acc1 = {0.f,0.f,0.f,0.f};
    #pragma unroll
    for (int c = 0; c < 8; ++c){
      uint32_t byte = (Abits[row*8 + c] >> (l4*8)) & 0xFFu;
      short8v af;
      #pragma unroll
      for (int b = 0; b < 8; ++b) af[b] = (short)(((byte >> b) & 1u) * 0x3F80u);
      short8v b0 = *(const short8v*)&zT[l15][c*32 + l4*8];
      short8v b1 = *(const short8v*)&zT[16 + l15][c*32 + l4*8];
      acc0 = __builtin_amdgcn_mfma_f32_16x16x32_bf16(af, b0, acc0, 0, 0, 0);
      acc1 = __builtin_amdgcn_mfma_f32_16x16x32_bf16(af, b1, acc1, 0, 0, 0);
    }
    #pragma unroll
    for (int r2 = 0; r2 < 4; ++r2){
      azf[rt*16 + l4*4 + r2][l15]      = acc0[r2];
      azf[rt*16 + l4*4 + r2][16 + l15] = acc1[r2];
    }
  }
  __syncthreads();

  int r = tid >> 5, h = tid & 31;

  // ---- phase 4: h = relu(AZ @ Wd1 + bd1) -> hT (overwrites zT) ----
  {
    float w[HH];
    #pragma unroll
    for (int hh = 0; hh < HH; ++hh) w[hh] = wd1s[hh*HH + h];
    unsigned short hloc[16];
    #pragma unroll
    for (int rt2 = 0; rt2 < 16; ++rt2){
      int i = rt2*16 + r;
      const float4v* arow = (const float4v*)&azf[i][0];
      float hv = bd1s[h];
      #pragma unroll
      for (int q = 0; q < 8; ++q){
        float4v a = arow[q];
        hv = fmaf(a.x, w[q*4+0], hv);
        hv = fmaf(a.y, w[q*4+1], hv);
        hv = fmaf(a.z, w[q*4+2], hv);
        hv = fmaf(a.w, w[q*4+3], hv);
      }
      hloc[rt2] = f2bf(fmaxf(hv, 0.f));
    }
    __syncthreads();   // all azf reads done before zT overwrite is visible? (zT==hT distinct from azf; barrier orders zT reads in phase 3 vs writes here — already one barrier above; this one orders azf reads vs phase-5 writes)
    #pragma unroll
    for (int rt2 = 0; rt2 < 16; ++rt2) zT[h][rt2*16 + r] = hloc[rt2];
  }
  __syncthreads();

  // ---- phase 5: Ah = A @ h via MFMA -> azf (overwrites AZ) ----
  #pragma unroll
  for (int rr = 0; rr < 2; ++rr){
    int rt = wvid*2 + rr;
    int row = rt*16 + l15;
    float4v acc0 = {0.f,0.f,0.f,0.f}, acc1 = {0.f,0.f,0.f,0.f};
    #pragma unroll
    for (int c = 0; c < 8; ++c){
      uint32_t byte = (Abits[row*8 + c] >> (l4*8)) & 0xFFu;
      short8v af;
      #pragma unroll
      for (int b = 0; b < 8; ++b) af[b] = (short)(((byte >> b) & 1u) * 0x3F80u);
      short8v b0 = *(const short8v*)&zT[l15][c*32 + l4*8];
      short8v b1 = *(const short8v*)&zT[16 + l15][c*32 + l4*8];
      acc0 = __builtin_amdgcn_mfma_f32_16x16x32_bf16(af, b0, acc0, 0, 0, 0);
      acc1 = __builtin_amdgcn_mfma_f32_16x16x32_bf16(af, b1, acc1, 0, 0, 0);
    }
    #pragma unroll
    for (int r2 = 0; r2 < 4; ++r2){
      azf[rt*16 + l4*4 + r2][l15]      = acc0[r2];
      azf[rt*16 + l4*4 + r2][16 + l15] = acc1[r2];
    }
  }
  __syncthreads();

  // ---- phase 6: Xmu = Ah @ Wd2 + bd2 ; squared error ; reduce ----
  float part = 0.f;
  if (h < FF){
    float w2[HH];
    #pragma unroll
    for (int hh = 0; hh < HH; ++hh) w2[hh] = wd2s[hh*FF + h];
    #pragma unroll
    for (int rt2 = 0; rt2 < 16; ++rt2){
      int i = rt2*16 + r;
      const float4v* arow = (const float4v*)&azf[i][0];
      float xm = bd2s[h];
      #pragma unroll
      for (int q = 0; q < 8; ++q){
        float4v a = arow[q];
        xm = fmaf(a.x, w2[q*4+0], xm);
        xm = fmaf(a.y, w2[q*4+1], xm);
        xm = fmaf(a.z, w2[q*4+2], xm);
        xm = fmaf(a.w, w2[q*4+3], xm);
      }
      float d = xm - X[((size_t)g*NN + i)*FF + h];
      part = fmaf(d, d, part);
    }
  }
  float* red = (float*)Abits;
  red[tid] = part;
  __syncthreads();
  for (int s = 256; s > 0; s >>= 1){
    if (tid < s) red[tid] += red[tid + s];
    __syncthreads();
  }
  if (tid == 0) ws[W_PART + it*GG + g] = red[0];
}

// ---------- K5: final loss reduction ----------
__global__ void k_final(float* __restrict__ out, const float* __restrict__ ws){
  int tid = threadIdx.x;
  double s = 0.0;
  for (int i = tid; i < NS*GG; i += 512) s += (double)ws[W_PART + i];
  __shared__ double rd[512];
  rd[tid] = s;
  __syncthreads();
  for (int st = 256; st > 0; st >>= 1){
    if (tid < st) rd[tid] += rd[tid + st];
    __syncthreads();
  }
  if (tid == 0) out[O_LOSS] = (float)(rd[0] * (0.5/6400.0));
}

extern "C" void kernel_launch(void* const* d_in, const int* in_sizes, int n_in,
                              void* d_out, int out_size, void* d_ws, size_t ws_size,
                              hipStream_t stream){
  const float* X   = (const float*)d_in[0];
  const float* Wz1 = (const float*)d_in[1];
  const float* bz1 = (const float*)d_in[2];
  const float* Wz2 = (const float*)d_in[3];
  const float* bz2 = (const float*)d_in[4];
  const float* Wa1 = (const float*)d_in[5];
  const float* ba1 = (const float*)d_in[6];
  const float* Wth = (const float*)d_in[7];
  const float* Wal = (const float*)d_in[8];
  const float* bal = (const float*)d_in[9];
  const float* Wd1 = (const float*)d_in[10];
  const float* bd1 = (const float*)d_in[11];
  const float* Wd2 = (const float*)d_in[12];
  const float* bd2 = (const float*)d_in[13];
  const int* seed  = (const int*)d_in[14];
  float* out = (float*)d_out;
  float* ws  = (float*)d_ws;

  hipLaunchKernelGGL(k_encode, dim3(32,64), dim3(256), 0, stream,
                     X, Wz1, bz1, Wz2, bz2, Wa1, ba1, out, ws);
  hipLaunchKernelGGL(k_alpha, dim3(64), dim3(256), 0, stream, Wal, bal, out, ws);
  hipLaunchKernelGGL(k_theta, dim3(16,16,64), dim3(256), 0, stream, Wth, out, ws);
  hipLaunchKernelGGL(k_loop, dim3(64,100), dim3(512), 0, stream,
                     Wd1, bd1, Wd2, bd2, X, seed, out, ws);
  hipLaunchKernelGGL(k_final, dim3(1), dim3(512), 0, stream, out, ws);
}